// Round 2
// baseline (8160.683 us; speedup 1.0000x reference)
//
#include <hip/hip_runtime.h>
#include <hip/hip_bf16.h>

#define BB 32
#define NN 520
#define MM 520
#define EE 128
#define HH 8
#define DKK 16
#define FFH_ 512
#define NL_ 6
#define DEPOT_ 20
#define LL 40

// ---------------- embedding: depot/customer linear ----------------
__global__ __launch_bounds__(256) void embed_k(
    const float* __restrict__ dep, const float* __restrict__ cus,
    const float* __restrict__ Wd, const float* __restrict__ bd,
    const float* __restrict__ Wc3, const float* __restrict__ bc,
    float* __restrict__ x)
{
    int idx = blockIdx.x * 256 + threadIdx.x;   // < B*N*E = 2129920
    int e = idx & 127;
    int bn = idx >> 7;
    int n = bn % NN;
    int b = bn / NN;
    float a;
    if (n < DEPOT_) {
        a = bd[e];
        const float* f = dep + ((size_t)(b * DEPOT_ + n)) * 4;
        #pragma unroll
        for (int j = 0; j < 4; j++) a += f[j] * Wd[e * 4 + j];
    } else {
        a = bc[e];
        const float* f = cus + ((size_t)(b * 500 + (n - DEPOT_))) * 3;
        #pragma unroll
        for (int j = 0; j < 3; j++) a += f[j] * Wc3[e * 3 + j];
    }
    x[idx] = a;
}

// ---------------- generic GEMM: C[m,n] = sum_k A[m,k]*W[n,k] + bias[n] ----------------
#define TS 32
__global__ __launch_bounds__(256) void gemm_k(
    const float* __restrict__ A, int lda,
    const float* __restrict__ W, int ldw,
    const float* __restrict__ bias,
    float* __restrict__ C, int ldc,
    int K, int relu)
{
    __shared__ float As[TS][TS + 1];
    __shared__ float Ws[TS][TS + 1];
    int t = threadIdx.x;
    int tx = t & 15, ty = t >> 4;
    int m0 = blockIdx.y * TS, n0 = blockIdx.x * TS;
    float a00 = 0, a01 = 0, a10 = 0, a11 = 0;
    for (int k0 = 0; k0 < K; k0 += TS) {
        #pragma unroll
        for (int i = 0; i < 4; i++) {
            int idx = t + i * 256;
            int r = idx >> 5, c = idx & 31;
            As[r][c] = A[(size_t)(m0 + r) * lda + k0 + c];
            Ws[r][c] = W[(size_t)(n0 + r) * ldw + k0 + c];
        }
        __syncthreads();
        #pragma unroll
        for (int kk = 0; kk < TS; kk++) {
            float x0 = As[ty][kk], x1 = As[ty + 16][kk];
            float w0 = Ws[tx][kk], w1 = Ws[tx + 16][kk];
            a00 += x0 * w0; a01 += x0 * w1; a10 += x1 * w0; a11 += x1 * w1;
        }
        __syncthreads();
    }
    float b0 = bias ? bias[n0 + tx] : 0.0f;
    float b1 = bias ? bias[n0 + tx + 16] : 0.0f;
    float v00 = a00 + b0, v01 = a01 + b1, v10 = a10 + b0, v11 = a11 + b1;
    if (relu) {
        v00 = fmaxf(v00, 0.0f); v01 = fmaxf(v01, 0.0f);
        v10 = fmaxf(v10, 0.0f); v11 = fmaxf(v11, 0.0f);
    }
    C[(size_t)(m0 + ty) * ldc + n0 + tx] = v00;
    C[(size_t)(m0 + ty) * ldc + n0 + tx + 16] = v01;
    C[(size_t)(m0 + ty + 16) * ldc + n0 + tx] = v10;
    C[(size_t)(m0 + ty + 16) * ldc + n0 + tx + 16] = v11;
}

// ---------------- MHA: one block per (b,h,query-row) ----------------
__global__ __launch_bounds__(128) void mha_k(
    const float* __restrict__ Q, const float* __restrict__ K,
    const float* __restrict__ V, const float* __restrict__ mask,
    float* __restrict__ O, int Nq, int Nk)
{
    int idx = blockIdx.x;
    int n = idx % Nq;
    int bh = idx / Nq;
    int h = bh & 7;
    int b = bh >> 3;
    int t = threadIdx.x;
    __shared__ __align__(16) float qs[16];
    __shared__ float s[NN];
    __shared__ float rb[128];
    if (t < 16) qs[t] = Q[((size_t)(b * Nq + n)) * EE + h * 16 + t];
    __syncthreads();
    float4 qa = ((float4*)qs)[0], qb = ((float4*)qs)[1];
    float4 qc = ((float4*)qs)[2], qd = ((float4*)qs)[3];
    float lmax = -1e30f;
    for (int m = t; m < Nk; m += 128) {
        const float4* k4 = (const float4*)(K + ((size_t)(b * Nk + m)) * EE + h * 16);
        float4 k0 = k4[0], k1 = k4[1], k2 = k4[2], k3 = k4[3];
        float d = qa.x * k0.x + qa.y * k0.y + qa.z * k0.z + qa.w * k0.w
                + qb.x * k1.x + qb.y * k1.y + qb.z * k1.z + qb.w * k1.w
                + qc.x * k2.x + qc.y * k2.y + qc.z * k2.z + qc.w * k2.w
                + qd.x * k3.x + qd.y * k3.y + qd.z * k3.z + qd.w * k3.w;
        d *= 0.25f;  // 1/sqrt(16)
        if (mask) d += mask[((size_t)(b * Nq + n)) * Nk + m];
        s[m] = d;
        lmax = fmaxf(lmax, d);
    }
    rb[t] = lmax; __syncthreads();
    for (int st = 64; st > 0; st >>= 1) { if (t < st) rb[t] = fmaxf(rb[t], rb[t + st]); __syncthreads(); }
    float mx = rb[0];
    __syncthreads();
    float lsum = 0.0f;
    for (int m = t; m < Nk; m += 128) { float w = expf(s[m] - mx); s[m] = w; lsum += w; }
    rb[t] = lsum; __syncthreads();
    for (int st = 64; st > 0; st >>= 1) { if (t < st) rb[t] += rb[t + st]; __syncthreads(); }
    float inv = 1.0f / rb[0];
    __syncthreads();
    int d = t & 15, c = t >> 4;
    float acc = 0.0f;
    for (int m = c; m < Nk; m += 8)
        acc += s[m] * V[((size_t)(b * Nk + m)) * EE + h * 16 + d];
    rb[t] = acc; __syncthreads();
    if (t < 16) {
        float o = rb[t] + rb[16 + t] + rb[32 + t] + rb[48 + t]
                + rb[64 + t] + rb[80 + t] + rb[96 + t] + rb[112 + t];
        O[((size_t)(b * Nq + n)) * EE + h * 16 + t] = o * inv;
    }
}

// ---------------- InstanceNorm over node axis ----------------
__global__ __launch_bounds__(64) void inorm_k(
    const float* __restrict__ X, const float* __restrict__ Y,
    const float* __restrict__ g, const float* __restrict__ bb,
    float* __restrict__ Out)
{
    int be = blockIdx.x;
    int b = be >> 7, e = be & 127;
    int t = threadIdx.x;
    float vals[9];
    float s = 0.0f, s2 = 0.0f;
    int c = 0;
    for (int n = t; n < NN; n += 64) {
        size_t off = ((size_t)(b * NN + n)) * EE + e;
        float v = X[off] + Y[off];
        vals[c++] = v; s += v; s2 += v * v;
    }
    #pragma unroll
    for (int o = 32; o > 0; o >>= 1) { s += __shfl_down(s, o); s2 += __shfl_down(s2, o); }
    s = __shfl(s, 0); s2 = __shfl(s2, 0);
    float mu = s * (1.0f / NN);
    float var = s2 * (1.0f / NN) - mu * mu;
    float inv = rsqrtf(var + 1e-5f);
    float gg = g[e], bv = bb[e];
    c = 0;
    for (int n = t; n < NN; n += 64) {
        size_t off = ((size_t)(b * NN + n)) * EE + e;
        Out[off] = (vals[c++] - mu) * inv * gg + bv;
    }
}

__global__ void zero_k(float* p, int n) {
    int i = blockIdx.x * 256 + threadIdx.x;
    if (i < n) p[i] = 0.0f;
}

__global__ __launch_bounds__(128) void encsum_k(const float* __restrict__ enc, float* __restrict__ esum) {
    int b = blockIdx.x, ch = blockIdx.y, t = threadIdx.x;
    float a = 0.0f;
    for (int i = 0; i < 65; i++) {
        int n = ch * 65 + i;
        a += enc[((size_t)(b * NN + n)) * EE + t];
    }
    atomicAdd(&esum[b * EE + t], a);
}

// mt[b,e] = sum_f (esum[b,f]/N) * Wr[e, 128+f]
__global__ __launch_bounds__(128) void meanterm_k(
    const float* __restrict__ esum, const float* __restrict__ Wr, float* __restrict__ mt)
{
    int b = blockIdx.x, t = threadIdx.x;
    __shared__ float em[128];
    em[t] = esum[b * EE + t] * (1.0f / NN);
    __syncthreads();
    const float* w = Wr + (size_t)t * 257 + 128;
    float a = 0.0f;
    for (int f = 0; f < 128; f++) a += em[f] * w[f];
    mt[b * EE + t] = a;
}

__global__ __launch_bounds__(128) void subtour_k(
    const float* __restrict__ enc, const int* __restrict__ subn,
    const int* __restrict__ subl, float* __restrict__ subm)
{
    int bm = blockIdx.x;
    int b = bm / MM;
    int t = threadIdx.x;
    int len = subl[bm];
    float acc = 0.0f; int cnt = 0;
    for (int l = 0; l < LL; l++) {
        int node = subn[(size_t)bm * LL + l];
        if (l < len && node >= DEPOT_) {
            acc += enc[((size_t)(b * NN + node)) * EE + t];
            cnt++;
        }
    }
    float cf = (float)(cnt < 1 ? 1 : cnt);
    subm[(size_t)bm * EE + t] = acc / cf;
}

__global__ __launch_bounds__(128) void decq_k(
    const float* __restrict__ enc, const float* __restrict__ subm,
    const float* __restrict__ mterm, const int* __restrict__ cur,
    const float* __restrict__ loadv, const int* __restrict__ sel,
    const float* __restrict__ Wl, const float* __restrict__ Wr,
    float* __restrict__ out)
{
    int bm = blockIdx.x;
    int b = bm / MM;
    int t = threadIdx.x;
    __shared__ float le[128], sm[128];
    int cn = cur[bm];
    le[t] = enc[((size_t)(b * NN + cn)) * EE + t];
    sm[t] = subm[(size_t)bm * EE + t];
    __syncthreads();
    int s2v = sel[(size_t)bm * 4 + 2];   // selected[:,:,-2]
    bool flag = (s2v >= DEPOT_) && (cn < DEPOT_);
    float q;
    if (flag) {
        const float* w = Wl + (size_t)t * 256;
        float a = 0.0f;
        for (int f = 0; f < 128; f++) a += le[f] * w[f];
        for (int f = 0; f < 128; f++) a += sm[f] * w[128 + f];
        q = a;
    } else {
        const float* w = Wr + (size_t)t * 257;
        float a = mterm[b * EE + t] + loadv[bm] * w[256];
        for (int f = 0; f < 128; f++) a += le[f] * w[f];
        q = a;
    }
    out[(size_t)bm * EE + t] = q;
}

// ---------------- final: score @ encoded^T -> clip*tanh + mask -> softmax ----------------
__global__ __launch_bounds__(256) void score_k(
    const float* __restrict__ score, const float* __restrict__ enc,
    const float* __restrict__ mask, float* __restrict__ out)
{
    int bm = blockIdx.x;
    int b = bm / MM;
    int t = threadIdx.x;
    __shared__ __align__(16) float sc[128];
    __shared__ float sv[NN];
    __shared__ float rb[256];
    if (t < 128) sc[t] = score[(size_t)bm * EE + t];
    __syncthreads();
    float lmax = -1e30f;
    for (int n = t; n < NN; n += 256) {
        const float4* e4 = (const float4*)(enc + ((size_t)(b * NN + n)) * EE);
        float d = 0.0f;
        #pragma unroll
        for (int j = 0; j < 32; j++) {
            float4 ev = e4[j];
            float4 s4 = ((const float4*)sc)[j];
            d += ev.x * s4.x + ev.y * s4.y + ev.z * s4.z + ev.w * s4.w;
        }
        float val = 10.0f * tanhf(d * 0.088388347648318447f) + mask[(size_t)bm * NN + n];
        sv[n] = val;
        lmax = fmaxf(lmax, val);
    }
    rb[t] = lmax; __syncthreads();
    for (int st = 128; st > 0; st >>= 1) { if (t < st) rb[t] = fmaxf(rb[t], rb[t + st]); __syncthreads(); }
    float mx = rb[0];
    __syncthreads();
    float lsum = 0.0f;
    for (int n = t; n < NN; n += 256) { float w = expf(sv[n] - mx); sv[n] = w; lsum += w; }
    rb[t] = lsum; __syncthreads();
    for (int st = 128; st > 0; st >>= 1) { if (t < st) rb[t] += rb[t + st]; __syncthreads(); }
    float inv = 1.0f / rb[0];
    for (int n = t; n < NN; n += 256)
        out[(size_t)bm * NN + n] = sv[n] * inv;
}

extern "C" void kernel_launch(void* const* d_in, const int* in_sizes, int n_in,
                              void* d_out, int out_size, void* d_ws, size_t ws_size,
                              hipStream_t stream)
{
    const float* depot = (const float*)d_in[0];
    const float* cust  = (const float*)d_in[1];
    const float* mask  = (const float*)d_in[2];
    const float* loadv = (const float*)d_in[3];
    const int*  cur   = (const int*)d_in[4];
    const int*  subn  = (const int*)d_in[5];
    const int*  subl  = (const int*)d_in[6];
    const int*  sel   = (const int*)d_in[7];
    const float* Wdep  = (const float*)d_in[8];
    const float* bdep  = (const float*)d_in[9];
    const float* Wcus  = (const float*)d_in[10];
    const float* bcus  = (const float*)d_in[11];
    const float* Wq    = (const float*)d_in[12];
    const float* Wk    = (const float*)d_in[13];
    const float* Wv    = (const float*)d_in[14];
    const float* Wc    = (const float*)d_in[15];
    const float* Wcb   = (const float*)d_in[16];
    const float* n1g   = (const float*)d_in[17];
    const float* n1b   = (const float*)d_in[18];
    const float* fW1   = (const float*)d_in[19];
    const float* fb1   = (const float*)d_in[20];
    const float* fW2   = (const float*)d_in[21];
    const float* fb2   = (const float*)d_in[22];
    const float* n2g   = (const float*)d_in[23];
    const float* n2b   = (const float*)d_in[24];
    const float* Wql   = (const float*)d_in[25];
    const float* Wqr   = (const float*)d_in[26];
    const float* dWk   = (const float*)d_in[27];
    const float* dWv   = (const float*)d_in[28];
    const float* dWc   = (const float*)d_in[29];
    const float* dWcb  = (const float*)d_in[30];

    const size_t SZ = (size_t)BB * NN * EE;           // 2,129,920
    float* f0 = (float*)d_ws;       // x / encoded
    float* f1 = f0 + SZ;            // q / k_d
    float* f2 = f1 + SZ;            // k / v_d
    float* f3 = f2 + SZ;            // v / encsum + meanterm
    float* f4 = f3 + SZ;            // mh,ff2 out / sub_mean, dec attn
    float* f5 = f4 + SZ;            // x1 / final_q, score
    float* big = f5 + SZ;           // ffh (B*N*FFH)

    dim3 g4(EE / TS, (BB * NN) / TS);     // (4, 520)
    dim3 g16(FFH_ / TS, (BB * NN) / TS);  // (16, 520)
    const int NBH = BB * HH * NN;         // 133,120

    embed_k<<<(BB * NN * EE) / 256, 256, 0, stream>>>(depot, cust, Wdep, bdep, Wcus, bcus, f0);

    for (int i = 0; i < NL_; i++) {
        const float* wq = Wq + (size_t)i * EE * EE;
        const float* wk = Wk + (size_t)i * EE * EE;
        const float* wv = Wv + (size_t)i * EE * EE;
        const float* wc = Wc + (size_t)i * EE * EE;
        gemm_k<<<g4, 256, 0, stream>>>(f0, EE, wq, EE, nullptr, f1, EE, EE, 0);
        gemm_k<<<g4, 256, 0, stream>>>(f0, EE, wk, EE, nullptr, f2, EE, EE, 0);
        gemm_k<<<g4, 256, 0, stream>>>(f0, EE, wv, EE, nullptr, f3, EE, EE, 0);
        mha_k<<<NBH, 128, 0, stream>>>(f1, f2, f3, nullptr, f4, NN, NN);
        gemm_k<<<g4, 256, 0, stream>>>(f4, EE, wc, EE, Wcb + i * EE, f1, EE, EE, 0);
        inorm_k<<<BB * EE, 64, 0, stream>>>(f0, f1, n1g + i * EE, n1b + i * EE, f5);
        gemm_k<<<g16, 256, 0, stream>>>(f5, EE, fW1 + (size_t)i * FFH_ * EE, EE, fb1 + i * FFH_, big, FFH_, EE, 1);
        gemm_k<<<g4, 256, 0, stream>>>(big, FFH_, fW2 + (size_t)i * EE * FFH_, FFH_, fb2 + i * EE, f1, EE, FFH_, 0);
        inorm_k<<<BB * EE, 64, 0, stream>>>(f5, f1, n2g + i * EE, n2b + i * EE, f0);
    }

    // ---- decoder ----
    gemm_k<<<g4, 256, 0, stream>>>(f0, EE, dWk, EE, nullptr, f1, EE, EE, 0);
    gemm_k<<<g4, 256, 0, stream>>>(f0, EE, dWv, EE, nullptr, f2, EE, EE, 0);

    zero_k<<<(BB * EE + 255) / 256, 256, 0, stream>>>(f3, BB * EE);
    encsum_k<<<dim3(BB, 8), 128, 0, stream>>>(f0, f3);
    meanterm_k<<<BB, 128, 0, stream>>>(f3, Wqr, f3 + BB * EE);

    subtour_k<<<BB * MM, 128, 0, stream>>>(f0, subn, subl, f4);
    decq_k<<<BB * MM, 128, 0, stream>>>(f0, f4, f3 + BB * EE, cur, loadv, sel, Wql, Wqr, f5);

    mha_k<<<NBH, 128, 0, stream>>>(f5, f1, f2, mask, f4, MM, NN);
    gemm_k<<<g4, 256, 0, stream>>>(f4, EE, dWc, EE, dWcb, f5, EE, EE, 0);

    score_k<<<BB * MM, 256, 0, stream>>>(f5, f0, mask, (float*)d_out);
}

// Round 3
// 3918.506 us; speedup vs baseline: 2.0826x; 2.0826x over previous
//
#include <hip/hip_runtime.h>
#include <hip/hip_bf16.h>

#define BB 32
#define NN 520
#define MM 520
#define EE 128
#define HH 8
#define DKK 16
#define FFH_ 512
#define NL_ 6
#define DEPOT_ 20
#define LL 40

// ---------------- embedding: depot/customer linear ----------------
__global__ __launch_bounds__(256) void embed_k(
    const float* __restrict__ dep, const float* __restrict__ cus,
    const float* __restrict__ Wd, const float* __restrict__ bd,
    const float* __restrict__ Wc3, const float* __restrict__ bc,
    float* __restrict__ x)
{
    int idx = blockIdx.x * 256 + threadIdx.x;   // < B*N*E = 2129920
    int e = idx & 127;
    int bn = idx >> 7;
    int n = bn % NN;
    int b = bn / NN;
    float a;
    if (n < DEPOT_) {
        a = bd[e];
        const float* f = dep + ((size_t)(b * DEPOT_ + n)) * 4;
        #pragma unroll
        for (int j = 0; j < 4; j++) a += f[j] * Wd[e * 4 + j];
    } else {
        a = bc[e];
        const float* f = cus + ((size_t)(b * 500 + (n - DEPOT_))) * 3;
        #pragma unroll
        for (int j = 0; j < 3; j++) a += f[j] * Wc3[e * 3 + j];
    }
    x[idx] = a;
}

// ---------------- generic GEMM: C[m,n] = sum_k A[m,k]*W[n,k] + bias[n] ----------------
#define TS 32
__global__ __launch_bounds__(256) void gemm_k(
    const float* __restrict__ A, int lda,
    const float* __restrict__ W, int ldw,
    const float* __restrict__ bias,
    float* __restrict__ C, int ldc,
    int K, int relu)
{
    __shared__ float As[TS][TS + 1];
    __shared__ float Ws[TS][TS + 1];
    int t = threadIdx.x;
    int tx = t & 15, ty = t >> 4;
    int m0 = blockIdx.y * TS, n0 = blockIdx.x * TS;
    float a00 = 0, a01 = 0, a10 = 0, a11 = 0;
    for (int k0 = 0; k0 < K; k0 += TS) {
        #pragma unroll
        for (int i = 0; i < 4; i++) {
            int idx = t + i * 256;
            int r = idx >> 5, c = idx & 31;
            As[r][c] = A[(size_t)(m0 + r) * lda + k0 + c];
            Ws[r][c] = W[(size_t)(n0 + r) * ldw + k0 + c];
        }
        __syncthreads();
        #pragma unroll
        for (int kk = 0; kk < TS; kk++) {
            float x0 = As[ty][kk], x1 = As[ty + 16][kk];
            float w0 = Ws[tx][kk], w1 = Ws[tx + 16][kk];
            a00 += x0 * w0; a01 += x0 * w1; a10 += x1 * w0; a11 += x1 * w1;
        }
        __syncthreads();
    }
    float b0 = bias ? bias[n0 + tx] : 0.0f;
    float b1 = bias ? bias[n0 + tx + 16] : 0.0f;
    float v00 = a00 + b0, v01 = a01 + b1, v10 = a10 + b0, v11 = a11 + b1;
    if (relu) {
        v00 = fmaxf(v00, 0.0f); v01 = fmaxf(v01, 0.0f);
        v10 = fmaxf(v10, 0.0f); v11 = fmaxf(v11, 0.0f);
    }
    C[(size_t)(m0 + ty) * ldc + n0 + tx] = v00;
    C[(size_t)(m0 + ty) * ldc + n0 + tx + 16] = v01;
    C[(size_t)(m0 + ty + 16) * ldc + n0 + tx] = v10;
    C[(size_t)(m0 + ty + 16) * ldc + n0 + tx + 16] = v11;
}

// ---------------- flash-style MHA ----------------
// grid (qtiles, H, B), 256 threads. thread t: row r = t>>2 (0..63), c4 = t&3.
// Q row in regs; K/V tiles in LDS; online softmax; P via LDS; O dims c4*4..+3.
#define TQ 64
#define TK 64
__global__ __launch_bounds__(256) void fmha_k(
    const float* __restrict__ Q, const float* __restrict__ K,
    const float* __restrict__ V, const float* __restrict__ mask,
    float* __restrict__ O, int Nq, int Nk)
{
    int qt = blockIdx.x, h = blockIdx.y, b = blockIdx.z;
    int t = threadIdx.x;
    int r = t >> 2;
    int c4 = t & 3;
    int q = qt * TQ + r;
    int qc = q < Nq ? q : (Nq - 1);

    __shared__ float Ks[TK][20];
    __shared__ float Vs[TK][20];
    __shared__ float Ps[TQ][68];

    float qreg[16];
    {
        const float4* qp = (const float4*)(Q + ((size_t)(b * Nq + qc)) * EE + h * 16);
        #pragma unroll
        for (int i = 0; i < 4; i++) {
            float4 v = qp[i];
            qreg[i * 4 + 0] = v.x; qreg[i * 4 + 1] = v.y;
            qreg[i * 4 + 2] = v.z; qreg[i * 4 + 3] = v.w;
        }
    }

    float acc0 = 0, acc1 = 0, acc2 = 0, acc3 = 0;
    float m_i = -1e30f, l_i = 0.0f;
    const float* mrow = mask ? (mask + ((size_t)(b * Nq + qc)) * Nk) : nullptr;

    int nkt = (Nk + TK - 1) / TK;
    for (int kt = 0; kt < nkt; kt++) {
        int k0 = kt * TK;
        {
            int kr = k0 + r; if (kr >= Nk) kr = Nk - 1;
            const float4* kp = (const float4*)(K + ((size_t)(b * Nk + kr)) * EE + h * 16);
            const float4* vp = (const float4*)(V + ((size_t)(b * Nk + kr)) * EE + h * 16);
            *((float4*)&Ks[r][c4 * 4]) = kp[c4];
            *((float4*)&Vs[r][c4 * 4]) = vp[c4];
        }
        __syncthreads();

        // scores for cols j = jj*4 + c4
        float s[16];
        #pragma unroll
        for (int jj = 0; jj < 16; jj++) {
            int j = jj * 4 + c4;
            float d = 0.0f;
            #pragma unroll
            for (int kq = 0; kq < 4; kq++) {
                float4 kk = *((const float4*)&Ks[j][kq * 4]);
                d += qreg[kq * 4 + 0] * kk.x + qreg[kq * 4 + 1] * kk.y
                   + qreg[kq * 4 + 2] * kk.z + qreg[kq * 4 + 3] * kk.w;
            }
            d *= 0.25f;
            int kcol = k0 + j;
            if (kcol < Nk) {
                if (mrow) d += mrow[kcol];
                s[jj] = d;
            } else {
                s[jj] = -1e30f;
            }
        }

        float mloc = s[0];
        #pragma unroll
        for (int jj = 1; jj < 16; jj++) mloc = fmaxf(mloc, s[jj]);
        mloc = fmaxf(mloc, __shfl_xor(mloc, 1));
        mloc = fmaxf(mloc, __shfl_xor(mloc, 2));
        float m_new = fmaxf(m_i, mloc);
        float alpha = expf(m_i - m_new);

        float ls = 0.0f;
        #pragma unroll
        for (int jj = 0; jj < 16; jj++) {
            float p = expf(s[jj] - m_new);
            ls += p;
            Ps[r][jj * 4 + c4] = p;
        }
        ls += __shfl_xor(ls, 1);
        ls += __shfl_xor(ls, 2);
        l_i = l_i * alpha + ls;
        m_i = m_new;
        acc0 *= alpha; acc1 *= alpha; acc2 *= alpha; acc3 *= alpha;
        __syncthreads();

        // PV: O[r][c4*4..+3] += sum_m P[r][m] * V[m][c4*4..+3]
        #pragma unroll
        for (int mq = 0; mq < 16; mq++) {
            float4 pv = *((const float4*)&Ps[r][mq * 4]);
            float4 v0 = *((const float4*)&Vs[mq * 4 + 0][c4 * 4]);
            float4 v1 = *((const float4*)&Vs[mq * 4 + 1][c4 * 4]);
            float4 v2 = *((const float4*)&Vs[mq * 4 + 2][c4 * 4]);
            float4 v3 = *((const float4*)&Vs[mq * 4 + 3][c4 * 4]);
            acc0 += pv.x * v0.x + pv.y * v1.x + pv.z * v2.x + pv.w * v3.x;
            acc1 += pv.x * v0.y + pv.y * v1.y + pv.z * v2.y + pv.w * v3.y;
            acc2 += pv.x * v0.z + pv.y * v1.z + pv.z * v2.z + pv.w * v3.z;
            acc3 += pv.x * v0.w + pv.y * v1.w + pv.z * v2.w + pv.w * v3.w;
        }
        __syncthreads();
    }

    if (q < Nq) {
        float inv = 1.0f / l_i;
        float4 o; o.x = acc0 * inv; o.y = acc1 * inv; o.z = acc2 * inv; o.w = acc3 * inv;
        ((float4*)(O + ((size_t)(b * Nq + q)) * EE + h * 16))[c4] = o;
    }
}

// ---------------- InstanceNorm over node axis ----------------
__global__ __launch_bounds__(64) void inorm_k(
    const float* __restrict__ X, const float* __restrict__ Y,
    const float* __restrict__ g, const float* __restrict__ bb,
    float* __restrict__ Out)
{
    int be = blockIdx.x;
    int b = be >> 7, e = be & 127;
    int t = threadIdx.x;
    float vals[9];
    float s = 0.0f, s2 = 0.0f;
    int c = 0;
    for (int n = t; n < NN; n += 64) {
        size_t off = ((size_t)(b * NN + n)) * EE + e;
        float v = X[off] + Y[off];
        vals[c++] = v; s += v; s2 += v * v;
    }
    #pragma unroll
    for (int o = 32; o > 0; o >>= 1) { s += __shfl_down(s, o); s2 += __shfl_down(s2, o); }
    s = __shfl(s, 0); s2 = __shfl(s2, 0);
    float mu = s * (1.0f / NN);
    float var = s2 * (1.0f / NN) - mu * mu;
    float inv = rsqrtf(var + 1e-5f);
    float gg = g[e], bv = bb[e];
    c = 0;
    for (int n = t; n < NN; n += 64) {
        size_t off = ((size_t)(b * NN + n)) * EE + e;
        Out[off] = (vals[c++] - mu) * inv * gg + bv;
    }
}

__global__ void zero_k(float* p, int n) {
    int i = blockIdx.x * 256 + threadIdx.x;
    if (i < n) p[i] = 0.0f;
}

__global__ __launch_bounds__(128) void encsum_k(const float* __restrict__ enc, float* __restrict__ esum) {
    int b = blockIdx.x, ch = blockIdx.y, t = threadIdx.x;
    float a = 0.0f;
    for (int i = 0; i < 65; i++) {
        int n = ch * 65 + i;
        a += enc[((size_t)(b * NN + n)) * EE + t];
    }
    atomicAdd(&esum[b * EE + t], a);
}

// mt[b,e] = sum_f (esum[b,f]/N) * Wr[e, 128+f]
__global__ __launch_bounds__(128) void meanterm_k(
    const float* __restrict__ esum, const float* __restrict__ Wr, float* __restrict__ mt)
{
    int b = blockIdx.x, t = threadIdx.x;
    __shared__ float em[128];
    em[t] = esum[b * EE + t] * (1.0f / NN);
    __syncthreads();
    const float* w = Wr + (size_t)t * 257 + 128;
    float a = 0.0f;
    for (int f = 0; f < 128; f++) a += em[f] * w[f];
    mt[b * EE + t] = a;
}

__global__ __launch_bounds__(128) void subtour_k(
    const float* __restrict__ enc, const int* __restrict__ subn,
    const int* __restrict__ subl, float* __restrict__ subm)
{
    int bm = blockIdx.x;
    int b = bm / MM;
    int t = threadIdx.x;
    int len = subl[bm];
    float acc = 0.0f; int cnt = 0;
    for (int l = 0; l < LL; l++) {
        int node = subn[(size_t)bm * LL + l];
        if (l < len && node >= DEPOT_) {
            acc += enc[((size_t)(b * NN + node)) * EE + t];
            cnt++;
        }
    }
    float cf = (float)(cnt < 1 ? 1 : cnt);
    subm[(size_t)bm * EE + t] = acc / cf;
}

__global__ __launch_bounds__(128) void decq_k(
    const float* __restrict__ enc, const float* __restrict__ subm,
    const float* __restrict__ mterm, const int* __restrict__ cur,
    const float* __restrict__ loadv, const int* __restrict__ sel,
    const float* __restrict__ Wl, const float* __restrict__ Wr,
    float* __restrict__ out)
{
    int bm = blockIdx.x;
    int b = bm / MM;
    int t = threadIdx.x;
    __shared__ float le[128], sm[128];
    int cn = cur[bm];
    le[t] = enc[((size_t)(b * NN + cn)) * EE + t];
    sm[t] = subm[(size_t)bm * EE + t];
    __syncthreads();
    int s2v = sel[(size_t)bm * 4 + 2];   // selected[:,:,-2]
    bool flag = (s2v >= DEPOT_) && (cn < DEPOT_);
    float q;
    if (flag) {
        const float* w = Wl + (size_t)t * 256;
        float a = 0.0f;
        for (int f = 0; f < 128; f++) a += le[f] * w[f];
        for (int f = 0; f < 128; f++) a += sm[f] * w[128 + f];
        q = a;
    } else {
        const float* w = Wr + (size_t)t * 257;
        float a = mterm[b * EE + t] + loadv[bm] * w[256];
        for (int f = 0; f < 128; f++) a += le[f] * w[f];
        q = a;
    }
    out[(size_t)bm * EE + t] = q;
}

// ---------------- final: score @ encoded^T -> clip*tanh + mask -> softmax ----------------
__global__ __launch_bounds__(256) void score_k(
    const float* __restrict__ score, const float* __restrict__ enc,
    const float* __restrict__ mask, float* __restrict__ out)
{
    int bm = blockIdx.x;
    int b = bm / MM;
    int t = threadIdx.x;
    __shared__ __align__(16) float sc[128];
    __shared__ float sv[NN];
    __shared__ float rb[256];
    if (t < 128) sc[t] = score[(size_t)bm * EE + t];
    __syncthreads();
    float lmax = -1e30f;
    for (int n = t; n < NN; n += 256) {
        const float4* e4 = (const float4*)(enc + ((size_t)(b * NN + n)) * EE);
        float d = 0.0f;
        #pragma unroll
        for (int j = 0; j < 32; j++) {
            float4 ev = e4[j];
            float4 s4 = ((const float4*)sc)[j];
            d += ev.x * s4.x + ev.y * s4.y + ev.z * s4.z + ev.w * s4.w;
        }
        float val = 10.0f * tanhf(d * 0.088388347648318447f) + mask[(size_t)bm * NN + n];
        sv[n] = val;
        lmax = fmaxf(lmax, val);
    }
    rb[t] = lmax; __syncthreads();
    for (int st = 128; st > 0; st >>= 1) { if (t < st) rb[t] = fmaxf(rb[t], rb[t + st]); __syncthreads(); }
    float mx = rb[0];
    __syncthreads();
    float lsum = 0.0f;
    for (int n = t; n < NN; n += 256) { float w = expf(sv[n] - mx); sv[n] = w; lsum += w; }
    rb[t] = lsum; __syncthreads();
    for (int st = 128; st > 0; st >>= 1) { if (t < st) rb[t] += rb[t + st]; __syncthreads(); }
    float inv = 1.0f / rb[0];
    for (int n = t; n < NN; n += 256)
        out[(size_t)bm * NN + n] = sv[n] * inv;
}

extern "C" void kernel_launch(void* const* d_in, const int* in_sizes, int n_in,
                              void* d_out, int out_size, void* d_ws, size_t ws_size,
                              hipStream_t stream)
{
    const float* depot = (const float*)d_in[0];
    const float* cust  = (const float*)d_in[1];
    const float* mask  = (const float*)d_in[2];
    const float* loadv = (const float*)d_in[3];
    const int*  cur   = (const int*)d_in[4];
    const int*  subn  = (const int*)d_in[5];
    const int*  subl  = (const int*)d_in[6];
    const int*  sel   = (const int*)d_in[7];
    const float* Wdep  = (const float*)d_in[8];
    const float* bdep  = (const float*)d_in[9];
    const float* Wcus  = (const float*)d_in[10];
    const float* bcus  = (const float*)d_in[11];
    const float* Wq    = (const float*)d_in[12];
    const float* Wk    = (const float*)d_in[13];
    const float* Wv    = (const float*)d_in[14];
    const float* Wc    = (const float*)d_in[15];
    const float* Wcb   = (const float*)d_in[16];
    const float* n1g   = (const float*)d_in[17];
    const float* n1b   = (const float*)d_in[18];
    const float* fW1   = (const float*)d_in[19];
    const float* fb1   = (const float*)d_in[20];
    const float* fW2   = (const float*)d_in[21];
    const float* fb2   = (const float*)d_in[22];
    const float* n2g   = (const float*)d_in[23];
    const float* n2b   = (const float*)d_in[24];
    const float* Wql   = (const float*)d_in[25];
    const float* Wqr   = (const float*)d_in[26];
    const float* dWk   = (const float*)d_in[27];
    const float* dWv   = (const float*)d_in[28];
    const float* dWc   = (const float*)d_in[29];
    const float* dWcb  = (const float*)d_in[30];

    const size_t SZ = (size_t)BB * NN * EE;           // 2,129,920
    float* f0 = (float*)d_ws;       // x / encoded
    float* f1 = f0 + SZ;            // q / k_d
    float* f2 = f1 + SZ;            // k / v_d
    float* f3 = f2 + SZ;            // v / encsum + meanterm
    float* f4 = f3 + SZ;            // mh,ff2 out / sub_mean, dec attn
    float* f5 = f4 + SZ;            // x1 / final_q, score
    float* big = f5 + SZ;           // ffh (B*N*FFH)

    dim3 g4(EE / TS, (BB * NN) / TS);     // (4, 520)
    dim3 g16(FFH_ / TS, (BB * NN) / TS);  // (16, 520)
    dim3 gmha((NN + TQ - 1) / TQ, HH, BB);  // (9, 8, 32)

    embed_k<<<(BB * NN * EE) / 256, 256, 0, stream>>>(depot, cust, Wdep, bdep, Wcus, bcus, f0);

    for (int i = 0; i < NL_; i++) {
        const float* wq = Wq + (size_t)i * EE * EE;
        const float* wk = Wk + (size_t)i * EE * EE;
        const float* wv = Wv + (size_t)i * EE * EE;
        const float* wc = Wc + (size_t)i * EE * EE;
        gemm_k<<<g4, 256, 0, stream>>>(f0, EE, wq, EE, nullptr, f1, EE, EE, 0);
        gemm_k<<<g4, 256, 0, stream>>>(f0, EE, wk, EE, nullptr, f2, EE, EE, 0);
        gemm_k<<<g4, 256, 0, stream>>>(f0, EE, wv, EE, nullptr, f3, EE, EE, 0);
        fmha_k<<<gmha, 256, 0, stream>>>(f1, f2, f3, nullptr, f4, NN, NN);
        gemm_k<<<g4, 256, 0, stream>>>(f4, EE, wc, EE, Wcb + i * EE, f1, EE, EE, 0);
        inorm_k<<<BB * EE, 64, 0, stream>>>(f0, f1, n1g + i * EE, n1b + i * EE, f5);
        gemm_k<<<g16, 256, 0, stream>>>(f5, EE, fW1 + (size_t)i * FFH_ * EE, EE, fb1 + i * FFH_, big, FFH_, EE, 1);
        gemm_k<<<g4, 256, 0, stream>>>(big, FFH_, fW2 + (size_t)i * EE * FFH_, FFH_, fb2 + i * EE, f1, EE, FFH_, 0);
        inorm_k<<<BB * EE, 64, 0, stream>>>(f5, f1, n2g + i * EE, n2b + i * EE, f0);
    }

    // ---- decoder ----
    gemm_k<<<g4, 256, 0, stream>>>(f0, EE, dWk, EE, nullptr, f1, EE, EE, 0);
    gemm_k<<<g4, 256, 0, stream>>>(f0, EE, dWv, EE, nullptr, f2, EE, EE, 0);

    zero_k<<<(BB * EE + 255) / 256, 256, 0, stream>>>(f3, BB * EE);
    encsum_k<<<dim3(BB, 8), 128, 0, stream>>>(f0, f3);
    meanterm_k<<<BB, 128, 0, stream>>>(f3, Wqr, f3 + BB * EE);

    subtour_k<<<BB * MM, 128, 0, stream>>>(f0, subn, subl, f4);
    decq_k<<<BB * MM, 128, 0, stream>>>(f0, f4, f3 + BB * EE, cur, loadv, sel, Wql, Wqr, f5);

    fmha_k<<<gmha, 256, 0, stream>>>(f5, f1, f2, mask, f4, MM, NN);
    gemm_k<<<g4, 256, 0, stream>>>(f4, EE, dWc, EE, dWcb, f5, EE, EE, 0);

    score_k<<<BB * MM, 256, 0, stream>>>(f5, f0, mask, (float*)d_out);
}

// Round 4
// 3295.834 us; speedup vs baseline: 2.4761x; 1.1889x over previous
//
#include <hip/hip_runtime.h>
#include <hip/hip_bf16.h>

#define BB 32
#define NN 520
#define MM 520
#define EE 128
#define HH 8
#define DKK 16
#define FFH_ 512
#define NL_ 6
#define DEPOT_ 20
#define LL 40

// ---------------- embedding: depot/customer linear ----------------
__global__ __launch_bounds__(256) void embed_k(
    const float* __restrict__ dep, const float* __restrict__ cus,
    const float* __restrict__ Wd, const float* __restrict__ bd,
    const float* __restrict__ Wc3, const float* __restrict__ bc,
    float* __restrict__ x)
{
    int idx = blockIdx.x * 256 + threadIdx.x;   // < B*N*E = 2129920
    int e = idx & 127;
    int bn = idx >> 7;
    int n = bn % NN;
    int b = bn / NN;
    float a;
    if (n < DEPOT_) {
        a = bd[e];
        const float* f = dep + ((size_t)(b * DEPOT_ + n)) * 4;
        #pragma unroll
        for (int j = 0; j < 4; j++) a += f[j] * Wd[e * 4 + j];
    } else {
        a = bc[e];
        const float* f = cus + ((size_t)(b * 500 + (n - DEPOT_))) * 3;
        #pragma unroll
        for (int j = 0; j < 3; j++) a += f[j] * Wc3[e * 3 + j];
    }
    x[idx] = a;
}

// ---------------- 64x64-tile GEMM: C[m,n] = sum_k A[m,k]*W[n,k] + bias[n] ----------------
// 256 threads, 4x4 micro-tile, K-step 32, float2 LDS reads (pad 36 keeps 16B align).
#define GT 64
#define GK 32
#define GP 36
__global__ __launch_bounds__(256) void gemm64_k(
    const float* __restrict__ A, int lda,
    const float* __restrict__ W, int ldw,
    const float* __restrict__ bias,
    float* __restrict__ C, int ldc,
    int K, int relu)
{
    __shared__ float As[GT][GP];
    __shared__ float Ws[GT][GP];
    int t = threadIdx.x;
    int tx = t & 15, ty = t >> 4;
    int m0 = blockIdx.y * GT, n0 = blockIdx.x * GT;
    int lr = t >> 2, lc = (t & 3) * 8;
    float acc[4][4];
    #pragma unroll
    for (int i = 0; i < 4; i++)
        #pragma unroll
        for (int j = 0; j < 4; j++) acc[i][j] = 0.0f;

    for (int k0 = 0; k0 < K; k0 += GK) {
        const float* Ap = A + (size_t)(m0 + lr) * lda + k0 + lc;
        const float* Wp = W + (size_t)(n0 + lr) * ldw + k0 + lc;
        float4 av0 = *((const float4*)Ap), av1 = *((const float4*)(Ap + 4));
        float4 wv0 = *((const float4*)Wp), wv1 = *((const float4*)(Wp + 4));
        *((float4*)&As[lr][lc]) = av0; *((float4*)&As[lr][lc + 4]) = av1;
        *((float4*)&Ws[lr][lc]) = wv0; *((float4*)&Ws[lr][lc + 4]) = wv1;
        __syncthreads();
        #pragma unroll
        for (int kk = 0; kk < GK; kk += 2) {
            float2 a0 = *((const float2*)&As[ty][kk]);
            float2 a1 = *((const float2*)&As[ty + 16][kk]);
            float2 a2 = *((const float2*)&As[ty + 32][kk]);
            float2 a3 = *((const float2*)&As[ty + 48][kk]);
            float2 w0 = *((const float2*)&Ws[tx][kk]);
            float2 w1 = *((const float2*)&Ws[tx + 16][kk]);
            float2 w2 = *((const float2*)&Ws[tx + 32][kk]);
            float2 w3 = *((const float2*)&Ws[tx + 48][kk]);
            acc[0][0] += a0.x * w0.x + a0.y * w0.y;
            acc[0][1] += a0.x * w1.x + a0.y * w1.y;
            acc[0][2] += a0.x * w2.x + a0.y * w2.y;
            acc[0][3] += a0.x * w3.x + a0.y * w3.y;
            acc[1][0] += a1.x * w0.x + a1.y * w0.y;
            acc[1][1] += a1.x * w1.x + a1.y * w1.y;
            acc[1][2] += a1.x * w2.x + a1.y * w2.y;
            acc[1][3] += a1.x * w3.x + a1.y * w3.y;
            acc[2][0] += a2.x * w0.x + a2.y * w0.y;
            acc[2][1] += a2.x * w1.x + a2.y * w1.y;
            acc[2][2] += a2.x * w2.x + a2.y * w2.y;
            acc[2][3] += a2.x * w3.x + a2.y * w3.y;
            acc[3][0] += a3.x * w0.x + a3.y * w0.y;
            acc[3][1] += a3.x * w1.x + a3.y * w1.y;
            acc[3][2] += a3.x * w2.x + a3.y * w2.y;
            acc[3][3] += a3.x * w3.x + a3.y * w3.y;
        }
        __syncthreads();
    }
    #pragma unroll
    for (int j = 0; j < 4; j++) {
        float bv = bias ? bias[n0 + tx + 16 * j] : 0.0f;
        #pragma unroll
        for (int i = 0; i < 4; i++) {
            float v = acc[i][j] + bv;
            if (relu) v = fmaxf(v, 0.0f);
            C[(size_t)(m0 + ty + 16 * i) * ldc + n0 + tx + 16 * j] = v;
        }
    }
}

// ---------------- score GEMM (NT) with tanh epilogue ----------------
// C[b][m][n] = 10*tanh( dot(score[b,m,:], enc[b,n,:]) / sqrt(128) ), 64x64 tiles
__global__ __launch_bounds__(256) void sgemm_k(
    const float* __restrict__ A,    // score [B*520][128]
    const float* __restrict__ Enc,  // [B*520][128]
    float* __restrict__ C)          // [B][520][520]
{
    __shared__ float As[GT][GP];
    __shared__ float Ws[GT][GP];
    int t = threadIdx.x;
    int tx = t & 15, ty = t >> 4;
    int b = blockIdx.z;
    int m0 = blockIdx.y * GT, n0 = blockIdx.x * GT;
    int lr = t >> 2, lc = (t & 3) * 8;
    int mr = m0 + lr; if (mr >= NN) mr = NN - 1;
    int nr = n0 + lr; if (nr >= NN) nr = NN - 1;
    float acc[4][4];
    #pragma unroll
    for (int i = 0; i < 4; i++)
        #pragma unroll
        for (int j = 0; j < 4; j++) acc[i][j] = 0.0f;

    for (int k0 = 0; k0 < EE; k0 += GK) {
        const float* Ap = A + ((size_t)(b * NN + mr)) * EE + k0 + lc;
        const float* Wp = Enc + ((size_t)(b * NN + nr)) * EE + k0 + lc;
        float4 av0 = *((const float4*)Ap), av1 = *((const float4*)(Ap + 4));
        float4 wv0 = *((const float4*)Wp), wv1 = *((const float4*)(Wp + 4));
        *((float4*)&As[lr][lc]) = av0; *((float4*)&As[lr][lc + 4]) = av1;
        *((float4*)&Ws[lr][lc]) = wv0; *((float4*)&Ws[lr][lc + 4]) = wv1;
        __syncthreads();
        #pragma unroll
        for (int kk = 0; kk < GK; kk += 2) {
            float2 a0 = *((const float2*)&As[ty][kk]);
            float2 a1 = *((const float2*)&As[ty + 16][kk]);
            float2 a2 = *((const float2*)&As[ty + 32][kk]);
            float2 a3 = *((const float2*)&As[ty + 48][kk]);
            float2 w0 = *((const float2*)&Ws[tx][kk]);
            float2 w1 = *((const float2*)&Ws[tx + 16][kk]);
            float2 w2 = *((const float2*)&Ws[tx + 32][kk]);
            float2 w3 = *((const float2*)&Ws[tx + 48][kk]);
            acc[0][0] += a0.x * w0.x + a0.y * w0.y;
            acc[0][1] += a0.x * w1.x + a0.y * w1.y;
            acc[0][2] += a0.x * w2.x + a0.y * w2.y;
            acc[0][3] += a0.x * w3.x + a0.y * w3.y;
            acc[1][0] += a1.x * w0.x + a1.y * w0.y;
            acc[1][1] += a1.x * w1.x + a1.y * w1.y;
            acc[1][2] += a1.x * w2.x + a1.y * w2.y;
            acc[1][3] += a1.x * w3.x + a1.y * w3.y;
            acc[2][0] += a2.x * w0.x + a2.y * w0.y;
            acc[2][1] += a2.x * w1.x + a2.y * w1.y;
            acc[2][2] += a2.x * w2.x + a2.y * w2.y;
            acc[2][3] += a2.x * w3.x + a2.y * w3.y;
            acc[3][0] += a3.x * w0.x + a3.y * w0.y;
            acc[3][1] += a3.x * w1.x + a3.y * w1.y;
            acc[3][2] += a3.x * w2.x + a3.y * w2.y;
            acc[3][3] += a3.x * w3.x + a3.y * w3.y;
        }
        __syncthreads();
    }
    #pragma unroll
    for (int i = 0; i < 4; i++) {
        int m = m0 + ty + 16 * i;
        if (m >= NN) continue;
        #pragma unroll
        for (int j = 0; j < 4; j++) {
            int n = n0 + tx + 16 * j;
            if (n >= NN) continue;
            float v = 10.0f * tanhf(acc[i][j] * 0.088388347648318447f);
            C[((size_t)(b * NN + m)) * NN + n] = v;
        }
    }
}

// ---------------- row softmax: out = softmax(logits + mask) ----------------
__global__ __launch_bounds__(64) void smax_k(
    const float* __restrict__ L, const float* __restrict__ mask,
    float* __restrict__ out)
{
    int bm = blockIdx.x;
    int t = threadIdx.x;
    const float* Lr = L + (size_t)bm * NN;
    const float* Mr = mask + (size_t)bm * NN;
    float v[9];
    float mx = -1e30f;
    #pragma unroll
    for (int i = 0; i < 9; i++) {
        int idx = t + i * 64;
        if (idx < NN) { v[i] = Lr[idx] + Mr[idx]; mx = fmaxf(mx, v[i]); }
        else v[i] = -1e30f;
    }
    #pragma unroll
    for (int o = 32; o > 0; o >>= 1) mx = fmaxf(mx, __shfl_xor(mx, o));
    float s = 0.0f;
    #pragma unroll
    for (int i = 0; i < 9; i++) {
        int idx = t + i * 64;
        float e = (idx < NN) ? expf(v[i] - mx) : 0.0f;
        v[i] = e; s += e;
    }
    #pragma unroll
    for (int o = 32; o > 0; o >>= 1) s += __shfl_xor(s, o);
    float inv = 1.0f / s;
    #pragma unroll
    for (int i = 0; i < 9; i++) {
        int idx = t + i * 64;
        if (idx < NN) out[(size_t)bm * NN + idx] = v[i] * inv;
    }
}

// ---------------- flash-style MHA ----------------
#define TQ 64
#define TK 64
__global__ __launch_bounds__(256) void fmha_k(
    const float* __restrict__ Q, const float* __restrict__ K,
    const float* __restrict__ V, const float* __restrict__ mask,
    float* __restrict__ O, int Nq, int Nk)
{
    int qt = blockIdx.x, h = blockIdx.y, b = blockIdx.z;
    int t = threadIdx.x;
    int r = t >> 2;
    int c4 = t & 3;
    int q = qt * TQ + r;
    int qc = q < Nq ? q : (Nq - 1);

    __shared__ float Ks[TK][20];
    __shared__ float Vs[TK][20];
    __shared__ float Ps[TQ][68];

    float qreg[16];
    {
        const float4* qp = (const float4*)(Q + ((size_t)(b * Nq + qc)) * EE + h * 16);
        #pragma unroll
        for (int i = 0; i < 4; i++) {
            float4 v = qp[i];
            qreg[i * 4 + 0] = v.x; qreg[i * 4 + 1] = v.y;
            qreg[i * 4 + 2] = v.z; qreg[i * 4 + 3] = v.w;
        }
    }

    float acc0 = 0, acc1 = 0, acc2 = 0, acc3 = 0;
    float m_i = -1e30f, l_i = 0.0f;
    const float* mrow = mask ? (mask + ((size_t)(b * Nq + qc)) * Nk) : nullptr;

    int nkt = (Nk + TK - 1) / TK;
    for (int kt = 0; kt < nkt; kt++) {
        int k0 = kt * TK;
        {
            int kr = k0 + r; if (kr >= Nk) kr = Nk - 1;
            const float4* kp = (const float4*)(K + ((size_t)(b * Nk + kr)) * EE + h * 16);
            const float4* vp = (const float4*)(V + ((size_t)(b * Nk + kr)) * EE + h * 16);
            *((float4*)&Ks[r][c4 * 4]) = kp[c4];
            *((float4*)&Vs[r][c4 * 4]) = vp[c4];
        }
        __syncthreads();

        float s[16];
        #pragma unroll
        for (int jj = 0; jj < 16; jj++) {
            int j = jj * 4 + c4;
            float d = 0.0f;
            #pragma unroll
            for (int kq = 0; kq < 4; kq++) {
                float4 kk = *((const float4*)&Ks[j][kq * 4]);
                d += qreg[kq * 4 + 0] * kk.x + qreg[kq * 4 + 1] * kk.y
                   + qreg[kq * 4 + 2] * kk.z + qreg[kq * 4 + 3] * kk.w;
            }
            d *= 0.25f;
            int kcol = k0 + j;
            if (kcol < Nk) {
                if (mrow) d += mrow[kcol];
                s[jj] = d;
            } else {
                s[jj] = -1e30f;
            }
        }

        float mloc = s[0];
        #pragma unroll
        for (int jj = 1; jj < 16; jj++) mloc = fmaxf(mloc, s[jj]);
        mloc = fmaxf(mloc, __shfl_xor(mloc, 1));
        mloc = fmaxf(mloc, __shfl_xor(mloc, 2));
        float m_new = fmaxf(m_i, mloc);
        float alpha = expf(m_i - m_new);

        float ls = 0.0f;
        #pragma unroll
        for (int jj = 0; jj < 16; jj++) {
            float p = expf(s[jj] - m_new);
            ls += p;
            Ps[r][jj * 4 + c4] = p;
        }
        ls += __shfl_xor(ls, 1);
        ls += __shfl_xor(ls, 2);
        l_i = l_i * alpha + ls;
        m_i = m_new;
        acc0 *= alpha; acc1 *= alpha; acc2 *= alpha; acc3 *= alpha;
        __syncthreads();

        #pragma unroll
        for (int mq = 0; mq < 16; mq++) {
            float4 pv = *((const float4*)&Ps[r][mq * 4]);
            float4 v0 = *((const float4*)&Vs[mq * 4 + 0][c4 * 4]);
            float4 v1 = *((const float4*)&Vs[mq * 4 + 1][c4 * 4]);
            float4 v2 = *((const float4*)&Vs[mq * 4 + 2][c4 * 4]);
            float4 v3 = *((const float4*)&Vs[mq * 4 + 3][c4 * 4]);
            acc0 += pv.x * v0.x + pv.y * v1.x + pv.z * v2.x + pv.w * v3.x;
            acc1 += pv.x * v0.y + pv.y * v1.y + pv.z * v2.y + pv.w * v3.y;
            acc2 += pv.x * v0.z + pv.y * v1.z + pv.z * v2.z + pv.w * v3.z;
            acc3 += pv.x * v0.w + pv.y * v1.w + pv.z * v2.w + pv.w * v3.w;
        }
        __syncthreads();
    }

    if (q < Nq) {
        float inv = 1.0f / l_i;
        float4 o; o.x = acc0 * inv; o.y = acc1 * inv; o.z = acc2 * inv; o.w = acc3 * inv;
        ((float4*)(O + ((size_t)(b * Nq + q)) * EE + h * 16))[c4] = o;
    }
}

// ---------------- InstanceNorm over node axis ----------------
__global__ __launch_bounds__(64) void inorm_k(
    const float* __restrict__ X, const float* __restrict__ Y,
    const float* __restrict__ g, const float* __restrict__ bb,
    float* __restrict__ Out)
{
    int be = blockIdx.x;
    int b = be >> 7, e = be & 127;
    int t = threadIdx.x;
    float vals[9];
    float s = 0.0f, s2 = 0.0f;
    int c = 0;
    for (int n = t; n < NN; n += 64) {
        size_t off = ((size_t)(b * NN + n)) * EE + e;
        float v = X[off] + Y[off];
        vals[c++] = v; s += v; s2 += v * v;
    }
    #pragma unroll
    for (int o = 32; o > 0; o >>= 1) { s += __shfl_down(s, o); s2 += __shfl_down(s2, o); }
    s = __shfl(s, 0); s2 = __shfl(s2, 0);
    float mu = s * (1.0f / NN);
    float var = s2 * (1.0f / NN) - mu * mu;
    float inv = rsqrtf(var + 1e-5f);
    float gg = g[e], bv = bb[e];
    c = 0;
    for (int n = t; n < NN; n += 64) {
        size_t off = ((size_t)(b * NN + n)) * EE + e;
        Out[off] = (vals[c++] - mu) * inv * gg + bv;
    }
}

__global__ void zero_k(float* p, int n) {
    int i = blockIdx.x * 256 + threadIdx.x;
    if (i < n) p[i] = 0.0f;
}

__global__ __launch_bounds__(128) void encsum_k(const float* __restrict__ enc, float* __restrict__ esum) {
    int b = blockIdx.x, ch = blockIdx.y, t = threadIdx.x;
    float a = 0.0f;
    for (int i = 0; i < 65; i++) {
        int n = ch * 65 + i;
        a += enc[((size_t)(b * NN + n)) * EE + t];
    }
    atomicAdd(&esum[b * EE + t], a);
}

// mt[b,e] = sum_f (esum[b,f]/N) * Wr[e, 128+f]
__global__ __launch_bounds__(128) void meanterm_k(
    const float* __restrict__ esum, const float* __restrict__ Wr, float* __restrict__ mt)
{
    int b = blockIdx.x, t = threadIdx.x;
    __shared__ float em[128];
    em[t] = esum[b * EE + t] * (1.0f / NN);
    __syncthreads();
    const float* w = Wr + (size_t)t * 257 + 128;
    float a = 0.0f;
    for (int f = 0; f < 128; f++) a += em[f] * w[f];
    mt[b * EE + t] = a;
}

__global__ __launch_bounds__(128) void subtour_k(
    const float* __restrict__ enc, const int* __restrict__ subn,
    const int* __restrict__ subl, float* __restrict__ subm)
{
    int bm = blockIdx.x;
    int b = bm / MM;
    int t = threadIdx.x;
    int len = subl[bm];
    float acc = 0.0f; int cnt = 0;
    for (int l = 0; l < LL; l++) {
        int node = subn[(size_t)bm * LL + l];
        if (l < len && node >= DEPOT_) {
            acc += enc[((size_t)(b * NN + node)) * EE + t];
            cnt++;
        }
    }
    float cf = (float)(cnt < 1 ? 1 : cnt);
    subm[(size_t)bm * EE + t] = acc / cf;
}

__global__ __launch_bounds__(128) void decq_k(
    const float* __restrict__ enc, const float* __restrict__ subm,
    const float* __restrict__ mterm, const int* __restrict__ cur,
    const float* __restrict__ loadv, const int* __restrict__ sel,
    const float* __restrict__ Wl, const float* __restrict__ Wr,
    float* __restrict__ out)
{
    int bm = blockIdx.x;
    int b = bm / MM;
    int t = threadIdx.x;
    __shared__ float le[128], sm[128];
    int cn = cur[bm];
    le[t] = enc[((size_t)(b * NN + cn)) * EE + t];
    sm[t] = subm[(size_t)bm * EE + t];
    __syncthreads();
    int s2v = sel[(size_t)bm * 4 + 2];   // selected[:,:,-2]
    bool flag = (s2v >= DEPOT_) && (cn < DEPOT_);
    float q;
    if (flag) {
        const float* w = Wl + (size_t)t * 256;
        float a = 0.0f;
        for (int f = 0; f < 128; f++) a += le[f] * w[f];
        for (int f = 0; f < 128; f++) a += sm[f] * w[128 + f];
        q = a;
    } else {
        const float* w = Wr + (size_t)t * 257;
        float a = mterm[b * EE + t] + loadv[bm] * w[256];
        for (int f = 0; f < 128; f++) a += le[f] * w[f];
        q = a;
    }
    out[(size_t)bm * EE + t] = q;
}

extern "C" void kernel_launch(void* const* d_in, const int* in_sizes, int n_in,
                              void* d_out, int out_size, void* d_ws, size_t ws_size,
                              hipStream_t stream)
{
    const float* depot = (const float*)d_in[0];
    const float* cust  = (const float*)d_in[1];
    const float* mask  = (const float*)d_in[2];
    const float* loadv = (const float*)d_in[3];
    const int*  cur   = (const int*)d_in[4];
    const int*  subn  = (const int*)d_in[5];
    const int*  subl  = (const int*)d_in[6];
    const int*  sel   = (const int*)d_in[7];
    const float* Wdep  = (const float*)d_in[8];
    const float* bdep  = (const float*)d_in[9];
    const float* Wcus  = (const float*)d_in[10];
    const float* bcus  = (const float*)d_in[11];
    const float* Wq    = (const float*)d_in[12];
    const float* Wk    = (const float*)d_in[13];
    const float* Wv    = (const float*)d_in[14];
    const float* Wc    = (const float*)d_in[15];
    const float* Wcb   = (const float*)d_in[16];
    const float* n1g   = (const float*)d_in[17];
    const float* n1b   = (const float*)d_in[18];
    const float* fW1   = (const float*)d_in[19];
    const float* fb1   = (const float*)d_in[20];
    const float* fW2   = (const float*)d_in[21];
    const float* fb2   = (const float*)d_in[22];
    const float* n2g   = (const float*)d_in[23];
    const float* n2b   = (const float*)d_in[24];
    const float* Wql   = (const float*)d_in[25];
    const float* Wqr   = (const float*)d_in[26];
    const float* dWk   = (const float*)d_in[27];
    const float* dWv   = (const float*)d_in[28];
    const float* dWc   = (const float*)d_in[29];
    const float* dWcb  = (const float*)d_in[30];

    const size_t SZ = (size_t)BB * NN * EE;           // 2,129,920
    float* f0 = (float*)d_ws;       // x / encoded
    float* f1 = f0 + SZ;            // q / k_d / logits (spans f1..f5)
    float* f2 = f1 + SZ;            // k / v_d
    float* f3 = f2 + SZ;            // v / encsum + meanterm
    float* f4 = f3 + SZ;            // mh,ff2 out / sub_mean, dec attn
    float* f5 = f4 + SZ;            // x1 / final_q
    float* big = f5 + SZ;           // ffh (B*N*FFH) / dec score

    dim3 g4(EE / GT, (BB * NN) / GT);     // (2, 260)
    dim3 g16(FFH_ / GT, (BB * NN) / GT);  // (8, 260)
    dim3 gmha((NN + TQ - 1) / TQ, HH, BB);  // (9, 8, 32)
    dim3 gsc((NN + GT - 1) / GT, (NN + GT - 1) / GT, BB);  // (9, 9, 32)

    embed_k<<<(BB * NN * EE) / 256, 256, 0, stream>>>(depot, cust, Wdep, bdep, Wcus, bcus, f0);

    for (int i = 0; i < NL_; i++) {
        const float* wq = Wq + (size_t)i * EE * EE;
        const float* wk = Wk + (size_t)i * EE * EE;
        const float* wv = Wv + (size_t)i * EE * EE;
        const float* wc = Wc + (size_t)i * EE * EE;
        gemm64_k<<<g4, 256, 0, stream>>>(f0, EE, wq, EE, nullptr, f1, EE, EE, 0);
        gemm64_k<<<g4, 256, 0, stream>>>(f0, EE, wk, EE, nullptr, f2, EE, EE, 0);
        gemm64_k<<<g4, 256, 0, stream>>>(f0, EE, wv, EE, nullptr, f3, EE, EE, 0);
        fmha_k<<<gmha, 256, 0, stream>>>(f1, f2, f3, nullptr, f4, NN, NN);
        gemm64_k<<<g4, 256, 0, stream>>>(f4, EE, wc, EE, Wcb + i * EE, f1, EE, EE, 0);
        inorm_k<<<BB * EE, 64, 0, stream>>>(f0, f1, n1g + i * EE, n1b + i * EE, f5);
        gemm64_k<<<g16, 256, 0, stream>>>(f5, EE, fW1 + (size_t)i * FFH_ * EE, EE, fb1 + i * FFH_, big, FFH_, EE, 1);
        gemm64_k<<<g4, 256, 0, stream>>>(big, FFH_, fW2 + (size_t)i * EE * FFH_, FFH_, fb2 + i * EE, f1, EE, FFH_, 0);
        inorm_k<<<BB * EE, 64, 0, stream>>>(f5, f1, n2g + i * EE, n2b + i * EE, f0);
    }

    // ---- decoder ----
    gemm64_k<<<g4, 256, 0, stream>>>(f0, EE, dWk, EE, nullptr, f1, EE, EE, 0);
    gemm64_k<<<g4, 256, 0, stream>>>(f0, EE, dWv, EE, nullptr, f2, EE, EE, 0);

    zero_k<<<(BB * EE + 255) / 256, 256, 0, stream>>>(f3, BB * EE);
    encsum_k<<<dim3(BB, 8), 128, 0, stream>>>(f0, f3);
    meanterm_k<<<BB, 128, 0, stream>>>(f3, Wqr, f3 + BB * EE);

    subtour_k<<<BB * MM, 128, 0, stream>>>(f0, subn, subl, f4);
    decq_k<<<BB * MM, 128, 0, stream>>>(f0, f4, f3 + BB * EE, cur, loadv, sel, Wql, Wqr, f5);

    fmha_k<<<gmha, 256, 0, stream>>>(f5, f1, f2, mask, f4, MM, NN);
    // dec score -> big (keeps f1..f5 free for the logits matrix)
    gemm64_k<<<g4, 256, 0, stream>>>(f4, EE, dWc, EE, dWcb, big, EE, EE, 0);

    // logits (B x 520 x 520) at f1 (spans f1..f5; all dead now)
    sgemm_k<<<gsc, 256, 0, stream>>>(big, f0, f1);
    smax_k<<<BB * MM, 64, 0, stream>>>(f1, mask, (float*)d_out);
}